// Round 4
// baseline (380.076 us; speedup 1.0000x reference)
//
#include <hip/hip_runtime.h>
#include <stdint.h>

#define NUM_UNIQUE   256
#define NUM_SAMPLES  4096
#define NUM_QUBITS   64
#define BATCH_SIZE   1024
#define THREADS      1024
#define WAVES        (THREADS / 64)
#define CHUNKS       (NUM_SAMPLES / 64)      // 64 chunks of 64 samples
#define CHUNKS_PER_WAVE (CHUNKS / WAVES)     // 4

typedef int v4i __attribute__((ext_vector_type(4)));
typedef unsigned long long u64;

// R7 = R6 with ONE isolated change: drop the nontemporal hint on the samples
// stream. samples (268 MB) ~ L3 size (256 MB) and is re-read every bench
// iteration; `nt` guarantees a full HBM re-fetch per iteration, while plain
// loads let the Infinity Cache retain most of it across iterations. nt was
// bundled into the prior session's R3 (rotations+nt+chunkrot) and never
// isolated — this round isolates it.
// Micro: Gram accumulator split in two (breaks the 32-deep serial fma chain).
// Everything else (chassis, rotations, fenced ring publish, symmetric Gram,
// fused gather) is byte-identical to R6 (340.4 µs, absmax 1.9e-6).
__global__ __launch_bounds__(THREADS)
void energy_kernel(const int* __restrict__ samples,
                   const int* __restrict__ idx,
                   const float* __restrict__ bias,
                   const float* __restrict__ Kmat,
                   float* __restrict__ out)
{
    __shared__ float Klds[NUM_QUBITS * 65];      // +1 pad: 2-way = free
    __shared__ float KS[NUM_QUBITS * 33];        // Ksym rows, pad 33: 2-way = free
    __shared__ u64   words[WAVES][128];          // per-wave duplicated ring
    __shared__ float wsum[WAVES];
    __shared__ float uval;

    const int tid  = threadIdx.x;
    const int wave = tid >> 6;
    const int lane = tid & 63;
    const int c    = blockIdx.x;

    for (int t = tid; t < NUM_QUBITS * NUM_QUBITS; t += THREADS)
        Klds[(t >> 6) * 65 + (t & 63)] = Kmat[t];
    __syncthreads();

    // Ksym fold (d=32 pairs enumerated twice around the ring -> 0.5 weight)
    for (int t = tid; t < 64 * 32; t += THREADS) {
        int q = t >> 5, d = (t & 31) + 1, r = (q + d) & 63;
        float v = Klds[q * 65 + r] + Klds[r * 65 + q];
        KS[q * 33 + d] = (d == 32) ? 0.5f * v : v;
    }

    float rowsum = 0.0f;
    {
        const float* Krow = &Klds[lane * 65];
        #pragma unroll
        for (int r = 0; r < 64; ++r) rowsum += Krow[r];
    }
    __syncthreads();                             // KS ready

    const float* ks = &KS[lane * 33];            // ks[d], base + imm offsets
    u64* wrow       = &words[wave][0];
    const u64* wp   = &words[wave][lane];        // wp[d] = B_{(lane+d)&63}

    float pcacc0 = 0.0f, pcacc1 = 0.0f;  // split: breaks serial fma chain
    int   cnt    = 0;                    // ones of qubit `lane`, this wave's 256 samples

    const int loadrot  = (3 * wave + 5 * c) & 15;   // intra-chunk phase stagger
    const int chunkrot = (13 * c) & 63;             // chunk-order stagger

    for (int ci = 0; ci < CHUNKS_PER_WAVE; ++ci) {
        const int chunk = ((wave * CHUNKS_PER_WAVE + ci) + chunkrot) & 63;
        const v4i* cp = (const v4i*)(samples +
            ((size_t)c * NUM_SAMPLES + (size_t)chunk * 64) * NUM_QUBITS);

        // ---- coalesced, phase-staggered load + bit pack ----
        // PLAIN loads (no nt): allow L2/L3 retention of the read-mostly
        // samples stream across bench iterations.
        unsigned int m0 = 0, m1 = 0, m2 = 0, m3 = 0;
        #pragma unroll
        for (int i = 0; i < 16; ++i) {
            const int j = (i + loadrot) & 15;
            v4i v = cp[j * 64 + lane];
            m0 = (m0 << 1) | (unsigned int)(v.x & 1);
            m1 = (m1 << 1) | (unsigned int)(v.y & 1);
            m2 = (m2 << 1) | (unsigned int)(v.z & 1);
            m3 = (m3 << 1) | (unsigned int)(v.w & 1);
        }
        u64 W = (u64)m0 | ((u64)m1 << 16) | ((u64)m2 << 32) | ((u64)m3 << 48);

        // ---- 4-step shuffle transpose: lane q ends with bitmask B_q ----
        u64 B = 0ull;
        #pragma unroll
        for (int p = 0; p < 4; ++p) {
            u64 src = __shfl(W, 16 * p + (lane >> 2));
            B |= ((src >> (16 * (lane & 3))) & 0xFFFFull) << (16 * p);
        }

        cnt += (int)__popcll(B);

        // ---- fenced ring publish: ds_reads of THIS chunk must not hoist
        // above these writes (cross-lane dep invisible to per-thread alias
        // analysis). LDS is in-order per wave in HW; compile-time ordering
        // suffices — no barrier, no waitcnt drain.
        asm volatile("" ::: "memory");
        wrow[lane]      = B;
        wrow[lane + 64] = B;                     // duplicate: reads are base+imm
        asm volatile("" ::: "memory");

        // ---- symmetric Gram: 32 ring pairs, two independent fma chains ----
        #pragma unroll
        for (int d = 1; d <= 32; d += 2) {
            u64 br0 = wp[d];
            u64 br1 = wp[d + 1];
            int pc0 = (int)__popcll(B ^ br0);
            int pc1 = (int)__popcll(B ^ br1);
            pcacc0 = fmaf(ks[d],     (float)pc0, pcacc0);
            pcacc1 = fmaf(ks[d + 1], (float)pc1, pcacc1);
        }
    }

    // quad: sum_s s^T K s = 64*nchunk*sum(K) - 2*sum_pairs Ksym*pc
    // linear: bias_q * sum_s s_q = bias_q * (256 - 2*cnt)
    float contrib = 64.0f * (float)CHUNKS_PER_WAVE * rowsum
                  - 2.0f * (pcacc0 + pcacc1)
                  + bias[lane] * (float)(CHUNKS_PER_WAVE * 64 - 2 * cnt);

    #pragma unroll
    for (int off = 32; off > 0; off >>= 1)
        contrib += __shfl_down(contrib, off);

    if (lane == 0) wsum[wave] = contrib;
    __syncthreads();
    if (tid == 0) {
        float s = 0.0f;
        #pragma unroll
        for (int i = 0; i < WAVES; ++i) s += wsum[i];
        uval = s * (1.0f / NUM_SAMPLES);
    }
    __syncthreads();

    // ---- fused expand_unique_results: thread b handles batch entry b ----
    const float u = uval;
    if (idx[tid] == c) out[tid] = u;
}

extern "C" void kernel_launch(void* const* d_in, const int* in_sizes, int n_in,
                              void* d_out, int out_size, void* d_ws, size_t ws_size,
                              hipStream_t stream)
{
    const int*   samples = (const int*)d_in[0];
    const int*   idx     = (const int*)d_in[1];
    const float* bias    = (const float*)d_in[2];
    const float* Kmat    = (const float*)d_in[3];
    float* out = (float*)d_out;

    energy_kernel<<<NUM_UNIQUE, THREADS, 0, stream>>>(samples, idx, bias, Kmat, out);
}

// Round 5
// 339.613 us; speedup vs baseline: 1.1191x; 1.1191x over previous
//
#include <hip/hip_runtime.h>
#include <stdint.h>

#define NUM_UNIQUE   256
#define NUM_SAMPLES  4096
#define NUM_QUBITS   64
#define BATCH_SIZE   1024
#define THREADS      1024
#define WAVES        (THREADS / 64)
#define CHUNKS       (NUM_SAMPLES / 64)      // 64 chunks of 64 samples
#define CHUNKS_PER_WAVE (CHUNKS / WAVES)     // 4

typedef int v4i __attribute__((ext_vector_type(4)));
typedef unsigned long long u64;

// R8 = exact revert to R6 (340.4 µs measured, best of session).
// R7 isolated the nontemporal hint: removing it cost +40 µs. Root cause: the
// harness poison-fills 1.07 GB per iteration (>4x the 256 MiB L3), so the
// samples stream can never be cache-resident at kernel start; plain loads add
// allocation churn on a one-shot stream. nt restored.
// Kernel-time calibration from the R6<->R7 delta: energy kernel ~45-55 µs vs
// the 268 MB / 6.3 TB/s = 43 µs read floor -> at the memory roofline; the
// rest of dur_us is harness fill/restore overhead.
__global__ __launch_bounds__(THREADS)
void energy_kernel(const int* __restrict__ samples,
                   const int* __restrict__ idx,
                   const float* __restrict__ bias,
                   const float* __restrict__ Kmat,
                   float* __restrict__ out)
{
    __shared__ float Klds[NUM_QUBITS * 65];      // +1 pad: 2-way = free
    __shared__ float KS[NUM_QUBITS * 33];        // Ksym rows, pad 33: 2-way = free
    __shared__ u64   words[WAVES][128];          // per-wave duplicated ring
    __shared__ float wsum[WAVES];
    __shared__ float uval;

    const int tid  = threadIdx.x;
    const int wave = tid >> 6;
    const int lane = tid & 63;
    const int c    = blockIdx.x;

    for (int t = tid; t < NUM_QUBITS * NUM_QUBITS; t += THREADS)
        Klds[(t >> 6) * 65 + (t & 63)] = Kmat[t];
    __syncthreads();

    // Ksym fold (d=32 pairs enumerated twice around the ring -> 0.5 weight)
    for (int t = tid; t < 64 * 32; t += THREADS) {
        int q = t >> 5, d = (t & 31) + 1, r = (q + d) & 63;
        float v = Klds[q * 65 + r] + Klds[r * 65 + q];
        KS[q * 33 + d] = (d == 32) ? 0.5f * v : v;
    }

    float rowsum = 0.0f;
    {
        const float* Krow = &Klds[lane * 65];
        #pragma unroll
        for (int r = 0; r < 64; ++r) rowsum += Krow[r];
    }
    __syncthreads();                             // KS ready

    const float* ks = &KS[lane * 33];            // ks[d], base + imm offsets
    u64* wrow       = &words[wave][0];
    const u64* wp   = &words[wave][lane];        // wp[d] = B_{(lane+d)&63}

    float pcacc = 0.0f;   // sum over chunks,pairs of Ksym * popcount(B_q^B_r)
    int   cnt   = 0;      // ones of qubit `lane` over this wave's 256 samples

    const int loadrot  = (3 * wave + 5 * c) & 15;   // intra-chunk phase stagger
    const int chunkrot = (13 * c) & 63;             // chunk-order stagger

    for (int ci = 0; ci < CHUNKS_PER_WAVE; ++ci) {
        const int chunk = ((wave * CHUNKS_PER_WAVE + ci) + chunkrot) & 63;
        const v4i* cp = (const v4i*)(samples +
            ((size_t)c * NUM_SAMPLES + (size_t)chunk * 64) * NUM_QUBITS);

        // ---- coalesced, phase-staggered, nontemporal load + bit pack ----
        // iter i loads slice j=(i+loadrot)&15: concurrent wave-instrs across
        // the device spread over the 16 KB chunk instead of channel lockstep.
        unsigned int m0 = 0, m1 = 0, m2 = 0, m3 = 0;
        #pragma unroll
        for (int i = 0; i < 16; ++i) {
            const int j = (i + loadrot) & 15;
            v4i v = __builtin_nontemporal_load(cp + j * 64 + lane);
            m0 = (m0 << 1) | (unsigned int)(v.x & 1);
            m1 = (m1 << 1) | (unsigned int)(v.y & 1);
            m2 = (m2 << 1) | (unsigned int)(v.z & 1);
            m3 = (m3 << 1) | (unsigned int)(v.w & 1);
        }
        u64 W = (u64)m0 | ((u64)m1 << 16) | ((u64)m2 << 32) | ((u64)m3 << 48);

        // ---- 4-step shuffle transpose: lane q ends with bitmask B_q ----
        u64 B = 0ull;
        #pragma unroll
        for (int p = 0; p < 4; ++p) {
            u64 src = __shfl(W, 16 * p + (lane >> 2));
            B |= ((src >> (16 * (lane & 3))) & 0xFFFFull) << (16 * p);
        }

        cnt += (int)__popcll(B);

        // ---- fenced ring publish: ds_reads of THIS chunk must not hoist
        // above these writes (cross-lane dep invisible to per-thread alias
        // analysis). LDS is in-order per wave in HW; compile-time ordering
        // suffices — no barrier, no waitcnt drain.
        asm volatile("" ::: "memory");
        wrow[lane]      = B;
        wrow[lane + 64] = B;                     // duplicate: reads are base+imm
        asm volatile("" ::: "memory");

        // ---- symmetric Gram: 32 ring pairs instead of 64 rows ----
        #pragma unroll
        for (int d = 1; d <= 32; ++d) {
            u64 br = wp[d];
            int pc = (int)__popcll(B ^ br);
            pcacc = fmaf(ks[d], (float)pc, pcacc);
        }
    }

    // quad: sum_s s^T K s = 64*nchunk*sum(K) - 2*sum_pairs Ksym*pc
    // linear: bias_q * sum_s s_q = bias_q * (256 - 2*cnt)
    float contrib = 64.0f * (float)CHUNKS_PER_WAVE * rowsum - 2.0f * pcacc
                  + bias[lane] * (float)(CHUNKS_PER_WAVE * 64 - 2 * cnt);

    #pragma unroll
    for (int off = 32; off > 0; off >>= 1)
        contrib += __shfl_down(contrib, off);

    if (lane == 0) wsum[wave] = contrib;
    __syncthreads();
    if (tid == 0) {
        float s = 0.0f;
        #pragma unroll
        for (int i = 0; i < WAVES; ++i) s += wsum[i];
        uval = s * (1.0f / NUM_SAMPLES);
    }
    __syncthreads();

    // ---- fused expand_unique_results: thread b handles batch entry b ----
    const float u = uval;
    if (idx[tid] == c) out[tid] = u;
}

extern "C" void kernel_launch(void* const* d_in, const int* in_sizes, int n_in,
                              void* d_out, int out_size, void* d_ws, size_t ws_size,
                              hipStream_t stream)
{
    const int*   samples = (const int*)d_in[0];
    const int*   idx     = (const int*)d_in[1];
    const float* bias    = (const float*)d_in[2];
    const float* Kmat    = (const float*)d_in[3];
    float* out = (float*)d_out;

    energy_kernel<<<NUM_UNIQUE, THREADS, 0, stream>>>(samples, idx, bias, Kmat, out);
}